// Round 1
// baseline (1280.352 us; speedup 1.0000x reference)
//
#include <hip/hip_runtime.h>
#include <stdint.h>

#define L_LAYERS 16
#define QD 2048
#define BATCH 4096

typedef __attribute__((ext_vector_type(8))) __bf16 bf16x8;
typedef __attribute__((ext_vector_type(4))) float f32x4;
typedef __attribute__((address_space(3))) uint32_t lds32_t;
typedef const __attribute__((address_space(1))) uint32_t glob32_t;

// async global->LDS, 16B per lane. LDS dest is wave-uniform base + lane*16;
// callers must compute lptr = wavebase + lane*16 (contiguous lane order).
__device__ __forceinline__ void async_load16(const void* g, void* l) {
    __builtin_amdgcn_global_load_lds((glob32_t*)(uintptr_t)g, (lds32_t*)(uintptr_t)l,
                                     16, 0, 0);
}

// float -> bf16 bits, round-to-nearest-even (explicit, to avoid truncation
// variants of __float2bfloat16 across ROCm versions).
__device__ __forceinline__ unsigned short f2bf(float f) {
    uint32_t u = __float_as_uint(f);
    u += 0x7FFFu + ((u >> 16) & 1u);
    return (unsigned short)(u >> 16);
}

// ---------------------------------------------------------------------------
// scales[l][k] = cos(a0/2)*cos(a1/2)*cos(a2/2)
__global__ void scales_kernel(const float* __restrict__ ang, float* __restrict__ sc, int n) {
    int i = blockIdx.x * 256 + threadIdx.x;
    if (i < n) {
        float a0 = ang[3 * i + 0], a1 = ang[3 * i + 1], a2 = ang[3 * i + 2];
        sc[i] = __cosf(a0 * 0.5f) * __cosf(a1 * 0.5f) * __cosf(a2 * 0.5f);
    }
}

// fp32 input state -> bf16
__global__ void convert_in_kernel(const float* __restrict__ in,
                                  unsigned short* __restrict__ out, int n4) {
    int i = blockIdx.x * 256 + threadIdx.x;
    if (i < n4) {
        float4 v = ((const float4*)in)[i];
        ushort4 o;
        o.x = f2bf(v.x); o.y = f2bf(v.y); o.z = f2bf(v.z); o.w = f2bf(v.w);
        ((ushort4*)out)[i] = o;
    }
}

// 64x64 tile: dst[n][k] = bf16( src[k][n] * scale[k] )   (transpose + scale-fold)
__device__ __forceinline__ void conv_tile_body(const float* __restrict__ src,
                                               const float* __restrict__ srow,
                                               unsigned short* __restrict__ dst) {
    __shared__ __align__(16) unsigned short tile[64][72];  // 72: pad, keeps 16B-aligned rows
    const int t = threadIdx.x;
    const int k0 = blockIdx.y * 64, n0 = blockIdx.x * 64;
    const int r = t >> 4;           // 0..15
    const int c = (t & 15) * 4;     // 0..60
#pragma unroll
    for (int rr = 0; rr < 64; rr += 16) {
        int k = k0 + r + rr;
        float s = srow ? srow[k] : 1.0f;
        float4 v = *(const float4*)(src + (size_t)k * QD + n0 + c);
        tile[c + 0][r + rr] = f2bf(v.x * s);
        tile[c + 1][r + rr] = f2bf(v.y * s);
        tile[c + 2][r + rr] = f2bf(v.z * s);
        tile[c + 3][r + rr] = f2bf(v.w * s);
    }
    __syncthreads();
    const int wr = t >> 3;          // 0..31
    const int wc = (t & 7) * 8;     // 0..56
#pragma unroll
    for (int rr = 0; rr < 64; rr += 32) {
        *(float4*)(dst + (size_t)(n0 + wr + rr) * QD + k0 + wc) =
            *(const float4*)(&tile[wr + rr][wc]);
    }
}

// all 17 matrices in one launch (z = layer; z==16 -> measurement basis, no scale)
__global__ void convert_w_all(const float* __restrict__ W, const float* __restrict__ Mb,
                              const float* __restrict__ sc, unsigned short* __restrict__ out) {
    const int z = blockIdx.z;
    const float* src = (z < L_LAYERS) ? (W + (size_t)z * QD * QD) : Mb;
    const float* srow = (z < L_LAYERS) ? (sc + z * QD) : nullptr;
    unsigned short* dst = out + (size_t)z * QD * QD;
    conv_tile_body(src, srow, dst);
}

// single-matrix variant (fallback when ws is small)
__global__ void convert_w_one(const float* __restrict__ src, const float* __restrict__ srow,
                              unsigned short* __restrict__ dst) {
    conv_tile_body(src, srow, dst);
}

// ---------------------------------------------------------------------------
// C[M=4096][N=2048] = A[M][K] * Bt[N][K]^T, bf16 inputs, fp32 accumulate.
// 128x128 block tile, BK=32, 4 waves (2x2), each wave 4x4 of 16x16x32 MFMA.
template <int OUT_BF16>
__global__ __launch_bounds__(256, 2) void gemm_kernel(const unsigned short* __restrict__ A,
                                                      const unsigned short* __restrict__ Bt,
                                                      void* __restrict__ Cout) {
    __shared__ __align__(16) unsigned short ldsA[128 * 32];
    __shared__ __align__(16) unsigned short ldsB[128 * 32];
    const int t = threadIdx.x;
    const int n0 = blockIdx.x * 128;
    const int m0 = blockIdx.y * 128;
    const int lane = t & 63;
    const int wave = t >> 6;
    const int wm = (wave & 1) * 64;
    const int wn = (wave >> 1) * 64;
    const int fr = lane & 15;      // A: m within 16-tile; B: n within 16-tile; C: col
    const int quad = lane >> 4;    // k-group for A/B frags; row-group for C

    f32x4 acc[4][4] = {};

    // staging: thread t loads 16B at (row = t/4, kcol = (t%4)*8); rows 0-63 and 64-127
    const int sr = t >> 2;
    const int scol = (t & 3) * 8;
    const unsigned short* ga = A + (size_t)(m0 + sr) * QD + scol;
    const unsigned short* gb = Bt + (size_t)(n0 + sr) * QD + scol;
    unsigned short* la = ldsA + t * 8;   // byte offset t*16 (lane-contiguous per wave)
    unsigned short* lb = ldsB + t * 8;

    for (int k0 = 0; k0 < QD; k0 += 32) {
        __syncthreads();  // previous tile's compute done before overwrite
        async_load16(ga, la);
        async_load16(ga + 64 * QD, la + 64 * 32);
        async_load16(gb, lb);
        async_load16(gb + 64 * QD, lb + 64 * 32);
        ga += 32;
        gb += 32;
        __syncthreads();  // staging complete (compiler inserts vmcnt(0))

        bf16x8 af[4], bfr[4];
#pragma unroll
        for (int i = 0; i < 4; i++)
            af[i] = *(const bf16x8*)(ldsA + (wm + i * 16 + fr) * 32 + quad * 8);
#pragma unroll
        for (int j = 0; j < 4; j++)
            bfr[j] = *(const bf16x8*)(ldsB + (wn + j * 16 + fr) * 32 + quad * 8);
#pragma unroll
        for (int i = 0; i < 4; i++)
#pragma unroll
            for (int j = 0; j < 4; j++)
                acc[i][j] = __builtin_amdgcn_mfma_f32_16x16x32_bf16(af[i], bfr[j],
                                                                    acc[i][j], 0, 0, 0);
    }

    // epilogue: C/D layout col=lane&15, row=quad*4+reg  (m89/m91-verified)
#pragma unroll
    for (int i = 0; i < 4; i++) {
        const int gr = m0 + wm + i * 16 + quad * 4;
#pragma unroll
        for (int j = 0; j < 4; j++) {
            const int gc = n0 + wn + j * 16 + fr;
#pragma unroll
            for (int r = 0; r < 4; r++) {
                float v = acc[i][j][r];
                if (OUT_BF16)
                    ((unsigned short*)Cout)[(size_t)(gr + r) * QD + gc] = f2bf(v);
                else
                    ((float*)Cout)[(size_t)(gr + r) * QD + gc] = v;
            }
        }
    }
}

// ---------------------------------------------------------------------------
extern "C" void kernel_launch(void* const* d_in, const int* in_sizes, int n_in,
                              void* d_out, int out_size, void* d_ws, size_t ws_size,
                              hipStream_t stream) {
    const float* input_state = (const float*)d_in[0];  // [4096][2048]
    const float* angles      = (const float*)d_in[1];  // [16][2048][3]
    const float* W           = (const float*)d_in[2];  // [16][2048][2048]
    const float* Mb          = (const float*)d_in[3];  // [2048][2048]

    char* ws = (char*)d_ws;
    float* scales = (float*)ws;                       // 16*2048*4 = 128KB
    size_t off = 131072;
    unsigned short* s0 = (unsigned short*)(ws + off); off += (size_t)BATCH * QD * 2;
    unsigned short* s1 = (unsigned short*)(ws + off); off += (size_t)BATCH * QD * 2;
    unsigned short* Wb = (unsigned short*)(ws + off);
    const size_t mat = (size_t)QD * QD;
    const bool full = ws_size >= off + 17 * mat * 2;  // ~176 MB total

    scales_kernel<<<(L_LAYERS * QD + 255) / 256, 256, 0, stream>>>(angles, scales,
                                                                   L_LAYERS * QD);
    convert_in_kernel<<<(BATCH * QD / 4 + 255) / 256, 256, 0, stream>>>(
        input_state, s0, BATCH * QD / 4);

    if (full) {
        dim3 g(QD / 64, QD / 64, L_LAYERS + 1);
        convert_w_all<<<g, 256, 0, stream>>>(W, Mb, scales, Wb);
    }

    dim3 gg(QD / 128, BATCH / 128);  // 16 x 32 = 512 blocks
    unsigned short* cur = s0;
    unsigned short* nxt = s1;
    for (int l = 0; l < L_LAYERS; l++) {
        unsigned short* wb = full ? (Wb + (size_t)l * mat) : Wb;
        if (!full) {
            dim3 g(QD / 64, QD / 64, 1);
            convert_w_one<<<g, 256, 0, stream>>>(W + (size_t)l * mat, scales + l * QD, Wb);
        }
        gemm_kernel<1><<<gg, 256, 0, stream>>>(cur, wb, nxt);
        unsigned short* tmp = cur; cur = nxt; nxt = tmp;
    }
    unsigned short* mb = full ? (Wb + (size_t)L_LAYERS * mat) : Wb;
    if (!full) {
        dim3 g(QD / 64, QD / 64, 1);
        convert_w_one<<<g, 256, 0, stream>>>(Mb, nullptr, Wb);
    }
    gemm_kernel<0><<<gg, 256, 0, stream>>>(cur, mb, d_out);
}

// Round 2
// 1202.521 us; speedup vs baseline: 1.0647x; 1.0647x over previous
//
#include <hip/hip_runtime.h>
#include <stdint.h>

#define L_LAYERS 16
#define QD 2048
#define BATCH 4096

typedef __attribute__((ext_vector_type(8))) __bf16 bf16x8;
typedef __attribute__((ext_vector_type(4))) float f32x4;
typedef __attribute__((address_space(3))) uint32_t lds32_t;
typedef const __attribute__((address_space(1))) uint32_t glob32_t;

// async global->LDS, 16B per lane. LDS dest is wave-uniform base + lane*16;
// callers must compute lptr = wavebase + lane*16 (contiguous lane order).
__device__ __forceinline__ void async_load16(const void* g, void* l) {
    __builtin_amdgcn_global_load_lds((glob32_t*)(uintptr_t)g, (lds32_t*)(uintptr_t)l,
                                     16, 0, 0);
}

// float -> bf16 bits, round-to-nearest-even.
__device__ __forceinline__ unsigned short f2bf(float f) {
    uint32_t u = __float_as_uint(f);
    u += 0x7FFFu + ((u >> 16) & 1u);
    return (unsigned short)(u >> 16);
}

// ---------------------------------------------------------------------------
// scales[l][k] = cos(a0/2)*cos(a1/2)*cos(a2/2)
__global__ void scales_kernel(const float* __restrict__ ang, float* __restrict__ sc, int n) {
    int i = blockIdx.x * 256 + threadIdx.x;
    if (i < n) {
        float a0 = ang[3 * i + 0], a1 = ang[3 * i + 1], a2 = ang[3 * i + 2];
        sc[i] = __cosf(a0 * 0.5f) * __cosf(a1 * 0.5f) * __cosf(a2 * 0.5f);
    }
}

// fp32 input state -> bf16
__global__ void convert_in_kernel(const float* __restrict__ in,
                                  unsigned short* __restrict__ out, int n4) {
    int i = blockIdx.x * 256 + threadIdx.x;
    if (i < n4) {
        float4 v = ((const float4*)in)[i];
        ushort4 o;
        o.x = f2bf(v.x); o.y = f2bf(v.y); o.z = f2bf(v.z); o.w = f2bf(v.w);
        ((ushort4*)out)[i] = o;
    }
}

// 64x64 tile: dst[n][k] = bf16( src[k][n] * scale[k] )   (transpose + scale-fold)
__device__ __forceinline__ void conv_tile_body(const float* __restrict__ src,
                                               const float* __restrict__ srow,
                                               unsigned short* __restrict__ dst) {
    __shared__ __align__(16) unsigned short tile[64][72];  // pad keeps 16B-aligned rows
    const int t = threadIdx.x;
    const int k0 = blockIdx.y * 64, n0 = blockIdx.x * 64;
    const int r = t >> 4;           // 0..15
    const int c = (t & 15) * 4;     // 0..60
#pragma unroll
    for (int rr = 0; rr < 64; rr += 16) {
        int k = k0 + r + rr;
        float s = srow ? srow[k] : 1.0f;
        float4 v = *(const float4*)(src + (size_t)k * QD + n0 + c);
        tile[c + 0][r + rr] = f2bf(v.x * s);
        tile[c + 1][r + rr] = f2bf(v.y * s);
        tile[c + 2][r + rr] = f2bf(v.z * s);
        tile[c + 3][r + rr] = f2bf(v.w * s);
    }
    __syncthreads();
    const int wr = t >> 3;          // 0..31
    const int wc = (t & 7) * 8;     // 0..56
#pragma unroll
    for (int rr = 0; rr < 64; rr += 32) {
        *(float4*)(dst + (size_t)(n0 + wr + rr) * QD + k0 + wc) =
            *(const float4*)(&tile[wr + rr][wc]);
    }
}

// all 17 matrices in one launch (z = layer; z==16 -> measurement basis, no scale)
__global__ void convert_w_all(const float* __restrict__ W, const float* __restrict__ Mb,
                              const float* __restrict__ sc, unsigned short* __restrict__ out) {
    const int z = blockIdx.z;
    const float* src = (z < L_LAYERS) ? (W + (size_t)z * QD * QD) : Mb;
    const float* srow = (z < L_LAYERS) ? (sc + z * QD) : nullptr;
    unsigned short* dst = out + (size_t)z * QD * QD;
    conv_tile_body(src, srow, dst);
}

// single-matrix variant (fallback when ws is small)
__global__ void convert_w_one(const float* __restrict__ src, const float* __restrict__ srow,
                              unsigned short* __restrict__ dst) {
    conv_tile_body(src, srow, dst);
}

// ---------------------------------------------------------------------------
// C[M=4096][N=2048] = A[M][K] * Bt[N][K]^T, bf16 inputs, fp32 accumulate.
// 128x128 block tile, BK=64 (two stacked BK=32 panels of [128][32] in LDS so
// global_load_lds stays lane-contiguous and fragment reads keep the m97 bank
// profile), 4 waves (2x2), each wave 4x4 of 16x16x32 MFMA.
// Grid = 512 blocks -> 2 blocks/CU (grid-capped); BK=64 halves barrier-drain
// events per unit MFMA vs BK=32. LDS = 2 * 16 KB = 32 KB/block.
template <int OUT_BF16>
__global__ __launch_bounds__(256, 2) void gemm_kernel(const unsigned short* __restrict__ A,
                                                      const unsigned short* __restrict__ Bt,
                                                      void* __restrict__ Cout) {
    __shared__ __align__(16) unsigned short ldsA[128 * 64];  // panel p at p*4096
    __shared__ __align__(16) unsigned short ldsB[128 * 64];
    const int t = threadIdx.x;
    const int n0 = blockIdx.x * 128;
    const int m0 = blockIdx.y * 128;
    const int lane = t & 63;
    const int wave = t >> 6;
    const int wm = (wave & 1) * 64;
    const int wn = (wave >> 1) * 64;
    const int fr = lane & 15;      // A: m in 16-tile; B: n in 16-tile; C: col
    const int quad = lane >> 4;    // k-group for A/B frags; row-group for C

    f32x4 acc[4][4] = {};

    // staging: per call, thread t covers row (t>>2) in a 64-row half, 8 k-elems
    // at (t&3)*8; LDS dest = panelbase + halfbase + t*16B (lane-contiguous).
    const int sr = t >> 2;          // 0..63
    const int scol = (t & 3) * 8;   // 0,8,16,24
    const unsigned short* ga = A + (size_t)(m0 + sr) * QD + scol;
    const unsigned short* gb = Bt + (size_t)(n0 + sr) * QD + scol;
    unsigned short* la = ldsA + t * 8;
    unsigned short* lb = ldsB + t * 8;

    for (int k0 = 0; k0 < QD; k0 += 64) {
        __syncthreads();  // previous round's compute done before overwrite
        // A: panel0 (k 0..31) halves 0/1, panel1 (k 32..63) halves 0/1
        async_load16(ga, la);
        async_load16(ga + 64 * QD, la + 2048);
        async_load16(ga + 32, la + 4096);
        async_load16(ga + 32 + 64 * QD, la + 6144);
        async_load16(gb, lb);
        async_load16(gb + 64 * QD, lb + 2048);
        async_load16(gb + 32, lb + 4096);
        async_load16(gb + 32 + 64 * QD, lb + 6144);
        ga += 64;
        gb += 64;
        __syncthreads();  // staging complete (compiler inserts vmcnt(0))

#pragma unroll
        for (int kk = 0; kk < 2; kk++) {
            const unsigned short* pa = ldsA + kk * 4096;
            const unsigned short* pb = ldsB + kk * 4096;
            bf16x8 af[4], bfr[4];
#pragma unroll
            for (int i = 0; i < 4; i++)
                af[i] = *(const bf16x8*)(pa + (wm + i * 16 + fr) * 32 + quad * 8);
#pragma unroll
            for (int j = 0; j < 4; j++)
                bfr[j] = *(const bf16x8*)(pb + (wn + j * 16 + fr) * 32 + quad * 8);
#pragma unroll
            for (int i = 0; i < 4; i++)
#pragma unroll
                for (int j = 0; j < 4; j++)
                    acc[i][j] = __builtin_amdgcn_mfma_f32_16x16x32_bf16(af[i], bfr[j],
                                                                        acc[i][j], 0, 0, 0);
        }
    }

    // epilogue: C/D layout col=lane&15, row=quad*4+reg  (m89/m91-verified)
#pragma unroll
    for (int i = 0; i < 4; i++) {
        const int gr = m0 + wm + i * 16 + quad * 4;
#pragma unroll
        for (int j = 0; j < 4; j++) {
            const int gc = n0 + wn + j * 16 + fr;
#pragma unroll
            for (int r = 0; r < 4; r++) {
                float v = acc[i][j][r];
                if (OUT_BF16)
                    ((unsigned short*)Cout)[(size_t)(gr + r) * QD + gc] = f2bf(v);
                else
                    ((float*)Cout)[(size_t)(gr + r) * QD + gc] = v;
            }
        }
    }
}

// ---------------------------------------------------------------------------
extern "C" void kernel_launch(void* const* d_in, const int* in_sizes, int n_in,
                              void* d_out, int out_size, void* d_ws, size_t ws_size,
                              hipStream_t stream) {
    const float* input_state = (const float*)d_in[0];  // [4096][2048]
    const float* angles      = (const float*)d_in[1];  // [16][2048][3]
    const float* W           = (const float*)d_in[2];  // [16][2048][2048]
    const float* Mb          = (const float*)d_in[3];  // [2048][2048]

    char* ws = (char*)d_ws;
    float* scales = (float*)ws;                       // 16*2048*4 = 128KB
    size_t off = 131072;
    unsigned short* s0 = (unsigned short*)(ws + off); off += (size_t)BATCH * QD * 2;
    unsigned short* s1 = (unsigned short*)(ws + off); off += (size_t)BATCH * QD * 2;
    unsigned short* Wb = (unsigned short*)(ws + off);
    const size_t mat = (size_t)QD * QD;
    const bool full = ws_size >= off + 17 * mat * 2;  // ~176 MB total

    scales_kernel<<<(L_LAYERS * QD + 255) / 256, 256, 0, stream>>>(angles, scales,
                                                                   L_LAYERS * QD);
    convert_in_kernel<<<(BATCH * QD / 4 + 255) / 256, 256, 0, stream>>>(
        input_state, s0, BATCH * QD / 4);

    if (full) {
        dim3 g(QD / 64, QD / 64, L_LAYERS + 1);
        convert_w_all<<<g, 256, 0, stream>>>(W, Mb, scales, Wb);
    }

    dim3 gg(QD / 128, BATCH / 128);  // 16 x 32 = 512 blocks
    unsigned short* cur = s0;
    unsigned short* nxt = s1;
    for (int l = 0; l < L_LAYERS; l++) {
        unsigned short* wb = full ? (Wb + (size_t)l * mat) : Wb;
        if (!full) {
            dim3 g(QD / 64, QD / 64, 1);
            convert_w_one<<<g, 256, 0, stream>>>(W + (size_t)l * mat, scales + l * QD, Wb);
        }
        gemm_kernel<1><<<gg, 256, 0, stream>>>(cur, wb, nxt);
        unsigned short* tmp = cur; cur = nxt; nxt = tmp;
    }
    unsigned short* mb = full ? (Wb + (size_t)L_LAYERS * mat) : Wb;
    if (!full) {
        dim3 g(QD / 64, QD / 64, 1);
        convert_w_one<<<g, 256, 0, stream>>>(Mb, nullptr, Wb);
    }
    gemm_kernel<0><<<gg, 256, 0, stream>>>(cur, mb, d_out);
}